// Round 1
// 432.488 us; speedup vs baseline: 1.1243x; 1.1243x over previous
//
#include <hip/hip_runtime.h>

// LoRA attention: B=4, S=2048, E=1024, R=16, fp32 in/out.
// R6 changes vs R5:
//  - gemm_bt (128^2 tile, 2-phase, vmcnt(0)-drain per K-step; MfmaUtil 16%,
//    ~72% stall = m233 anatomy) replaced by gemm256: 256^2 tile, BK=64,
//    8 waves (2Mx4N), 128 KB LDS double-buffer, 8-phase schedule with
//    counted s_waitcnt vmcnt(4) at tile entry (never 0 in the main loop),
//    per-phase stage/ds_read/MFMA interleave, s_setprio(1) around MFMA
//    clusters (T3+T4+T5 per the verified m201 template, 1563 TF @4k).
//  - Fragment-major LDS layout retained (0 bank conflicts, linear
//    global_load_lds dest + pre-swizzled global source).
//  - XCD-aware swizzle retained. Guards replaced by k-clamped dummy stages
//    so vmcnt counts stay uniform across all iterations.
// Race-freedom per tile t (cur = t&1):
//  - entry: vmcnt(4) + barrier => tile t fully landed (4 newest in-flight
//    loads are tile t+2's A-halves), all prior ds_reads drained per-wave.
//  - ph0/ph1 stage t+1's B-halves into buf cur^1 (its old data was drained
//    before the entry barrier).
//  - after ph1: explicit lgkmcnt(0)+barrier => ALL waves' reads of buf cur
//    complete; ph2/ph3 may then overwrite cur's A-halves with tile t+2.

#define S_LEN 2048
#define E_DIM 1024

typedef __attribute__((ext_vector_type(8))) short short8;
typedef __attribute__((ext_vector_type(4))) float floatx4;

__device__ __forceinline__ unsigned short f2bf(float f) {
  union { float f; unsigned int u; } x; x.f = f;
  return (unsigned short)((x.u + 0x7fffu + ((x.u >> 16) & 1u)) >> 16);  // RNE
}
__device__ __forceinline__ float bf2f(unsigned short h) {
  union { unsigned int u; float f; } x; x.u = ((unsigned int)h) << 16;
  return x.f;
}

__device__ __forceinline__ void gld_lds16(const unsigned short* g, unsigned short* l) {
  __builtin_amdgcn_global_load_lds(
      (const __attribute__((address_space(1))) unsigned int*)(const void*)g,
      (__attribute__((address_space(3))) unsigned int*)(void*)l,
      16, 0, 0);
}

// C[m][n] = scale * (sum_k A[m][k]*B[n][k]  (+ LoRA: sum_r LA[m][r]*LB[n][r]))
// 256x256 tile, BK=64, 512 threads (8 waves: wr=wave>>2 in M, wc=wave&3 in N),
// per-wave output 128x64 (acc[8][4] of 16x16 fragments).
// LDS half-tile = 128 rows x 64 bf16, fragment-major: 16B chunk (row,kc),
// kc in [0,8), at chunk index (row>>4)*128 + kc*16 + (row&15); fragment
// (rowgroup i, ksub ks) is then ds_read_b128 at chunk i*128 + ks*64 + lane
// (lane-contiguous -> zero bank conflicts; measured 0 on the 128^2 version).
template<bool LORA, bool OUTF32, bool OWNM>
__global__ __launch_bounds__(512, 2) void gemm256(
    const unsigned short* __restrict__ A, const unsigned short* __restrict__ B,
    void* __restrict__ Cv,
    const unsigned short* __restrict__ LA, const unsigned short* __restrict__ LB,
    long lda, long ldb, long ldc, int K, float scale,
    long batA, long batB, long batC, long batLA, long batLB) {
  __shared__ alignas(16) unsigned short As[2][2][8192];  // [buf][half][128*64]
  __shared__ alignas(16) unsigned short Bs[2][2][8192];

  const int tid  = threadIdx.x;
  const int wave = tid >> 6, lane = tid & 63;
  const int quad = lane >> 4, l16 = lane & 15;
  const int wr = wave >> 2, wc = wave & 3;   // 2x4 waves, each 128x64
  const int bg = (wc & 1) * 4;               // B chunk row-group base in its half

  // XCD-aware swizzle: xcd = flat%8 owns a chunk of the M (or N) tiles and
  // sweeps the other dimension fastest. Per-z wg counts are multiples of 8.
  const int Nx = (int)gridDim.x, Ny = (int)gridDim.y;
  const int wg2 = (int)blockIdx.x + Nx * (int)blockIdx.y;
  const int xcd = wg2 & 7, ii = wg2 >> 3;
  int bx, by;
  if constexpr (OWNM) {
    const int lg = 31 - __clz(Nx);
    by = xcd * (Ny >> 3) + (ii >> lg);
    bx = ii & (Nx - 1);
  } else {
    const int lg = 31 - __clz(Ny);
    bx = xcd * (Nx >> 3) + (ii >> lg);
    by = ii & (Ny - 1);
  }
  const long m0 = (long)by * 256;
  const long n0 = (long)bx * 256;
  const unsigned short* Az = A + (long)blockIdx.z * batA;
  const unsigned short* Bz = B + (long)blockIdx.z * batB;

  floatx4 acc[8][4];
#pragma unroll
  for (int i = 0; i < 8; ++i)
#pragma unroll
    for (int j = 0; j < 4; ++j) acc[i][j] = (floatx4){0.f, 0.f, 0.f, 0.f};

  // Stage source mapping for chunk c = L*512 + tid (L=0,1):
  //   rowInHalf = (c>>7)*16 + (c&15)  (L=1 -> +64 rows), koff = ((c>>4)&7)*8
  const int c0r = ((tid >> 7) << 4) | (tid & 15);
  const int c0k = ((tid >> 4) & 7) << 3;
  const unsigned short* a0 = Az + (m0 + c0r) * lda + c0k;
  const unsigned short* b0 = Bz + (n0 + c0r) * ldb + c0k;

#define STG_A(bf, h, k0)                                                    \
  do {                                                                      \
    gld_lds16(a0 + (long)((h) * 128) * lda + (k0), &As[bf][h][tid * 8]);    \
    gld_lds16(a0 + (long)((h) * 128 + 64) * lda + (k0),                     \
              &As[bf][h][4096 + tid * 8]);                                  \
  } while (0)
#define STG_B(bf, h, k0)                                                    \
  do {                                                                      \
    gld_lds16(b0 + (long)((h) * 128) * ldb + (k0), &Bs[bf][h][tid * 8]);    \
    gld_lds16(b0 + (long)((h) * 128 + 64) * ldb + (k0),                     \
              &Bs[bf][h][4096 + tid * 8]);                                  \
  } while (0)

  // prologue: tile 0 (A+B) into buf0, tile 1 A-halves into buf1 (12 loads).
  STG_A(0, 0, 0); STG_A(0, 1, 0);
  STG_B(0, 0, 0); STG_B(0, 1, 0);
  STG_A(1, 0, 64); STG_A(1, 1, 64);

  const int NT = K >> 6;
#pragma unroll 2
  for (int t = 0; t < NT; ++t) {
    const int cur = t & 1;
    // k-clamped prefetch targets (dummy re-stage on the last tiles keeps the
    // vmcnt arithmetic uniform; dummies land in buffers never read again).
    const int kB = (t + 1 < NT ? t + 1 : NT - 1) << 6;
    const int kA = (t + 2 < NT ? t + 2 : NT - 1) << 6;
    const unsigned short* ra = &As[cur][wr][0];
    const unsigned short* rb = &Bs[cur][wc >> 1][0];

    // tile entry: 4 newest outstanding loads are tile t+2's A-halves;
    // everything older (incl. this tile's B-halves) has landed.
    asm volatile("s_waitcnt vmcnt(4)\n\ts_barrier" ::: "memory");

    short8 a_[8][2], b_[4][2];
    // ---- ph0: read A-lo + B-lo, stage next-tile B half0, MFMA q(0,0)
#pragma unroll
    for (int i = 0; i < 4; ++i)
#pragma unroll
      for (int ks = 0; ks < 2; ++ks)
        a_[i][ks] = *(const short8*)(ra + (i * 128 + ks * 64 + lane) * 8);
#pragma unroll
    for (int j = 0; j < 2; ++j)
#pragma unroll
      for (int ks = 0; ks < 2; ++ks)
        b_[j][ks] = *(const short8*)(rb + ((bg + j) * 128 + ks * 64 + lane) * 8);
    STG_B(cur ^ 1, 0, kB);
    asm volatile("s_barrier" ::: "memory");
    __builtin_amdgcn_s_setprio(1);
#pragma unroll
    for (int ks = 0; ks < 2; ++ks)
#pragma unroll
      for (int i = 0; i < 4; ++i)
#pragma unroll
        for (int j = 0; j < 2; ++j)
          acc[i][j] = __builtin_amdgcn_mfma_f32_16x16x32_bf16(a_[i][ks], b_[j][ks], acc[i][j], 0, 0, 0);
    __builtin_amdgcn_s_setprio(0);

    // ---- ph1: read A-hi + B-hi, stage next-tile B half1, MFMA q(0,1)
#pragma unroll
    for (int i = 4; i < 8; ++i)
#pragma unroll
      for (int ks = 0; ks < 2; ++ks)
        a_[i][ks] = *(const short8*)(ra + (i * 128 + ks * 64 + lane) * 8);
#pragma unroll
    for (int j = 2; j < 4; ++j)
#pragma unroll
      for (int ks = 0; ks < 2; ++ks)
        b_[j][ks] = *(const short8*)(rb + ((bg + j) * 128 + ks * 64 + lane) * 8);
    STG_B(cur ^ 1, 1, kB);
    asm volatile("s_barrier" ::: "memory");
    __builtin_amdgcn_s_setprio(1);
#pragma unroll
    for (int ks = 0; ks < 2; ++ks)
#pragma unroll
      for (int i = 0; i < 4; ++i)
#pragma unroll
        for (int j = 2; j < 4; ++j)
          acc[i][j] = __builtin_amdgcn_mfma_f32_16x16x32_bf16(a_[i][ks], b_[j][ks], acc[i][j], 0, 0, 0);
    __builtin_amdgcn_s_setprio(0);
    // all reads of buf[cur] are now drained chip-wide -> cur's A region free
    asm volatile("s_waitcnt lgkmcnt(0)\n\ts_barrier" ::: "memory");

    // ---- ph2: stage tile t+2 A half0 into cur, MFMA q(1,0)
    STG_A(cur, 0, kA);
    __builtin_amdgcn_s_setprio(1);
#pragma unroll
    for (int ks = 0; ks < 2; ++ks)
#pragma unroll
      for (int i = 4; i < 8; ++i)
#pragma unroll
        for (int j = 0; j < 2; ++j)
          acc[i][j] = __builtin_amdgcn_mfma_f32_16x16x32_bf16(a_[i][ks], b_[j][ks], acc[i][j], 0, 0, 0);
    __builtin_amdgcn_s_setprio(0);

    // ---- ph3: stage tile t+2 A half1 into cur, MFMA q(1,1)
    STG_A(cur, 1, kA);
    __builtin_amdgcn_s_setprio(1);
#pragma unroll
    for (int ks = 0; ks < 2; ++ks)
#pragma unroll
      for (int i = 4; i < 8; ++i)
#pragma unroll
        for (int j = 2; j < 4; ++j)
          acc[i][j] = __builtin_amdgcn_mfma_f32_16x16x32_bf16(a_[i][ks], b_[j][ks], acc[i][j], 0, 0, 0);
    __builtin_amdgcn_s_setprio(0);
  }

  if constexpr (LORA) {
    __syncthreads();  // drains vmcnt(0) (pending dummy stages) + all waves done
    const unsigned short* LAz = LA + (long)blockIdx.z * batLA;
    const unsigned short* LBz = LB + (long)blockIdx.z * batLB;
    // Fill buf0 with LoRA operands in the same fragment-major layout:
    // kc 0..1 = ranks 0..15, kc >= 2 zero (MFMA ks=0 covers k 0..31).
#pragma unroll
    for (int cc = 0; cc < 4; ++cc) {
      const int c = cc * 512 + tid;
      const int h = c >> 10, ci = c & 1023;
      const int kc = (ci >> 4) & 7;
      const int row = h * 128 + ((ci >> 7) << 4) + (ci & 15);
      uint4 va, vb_;
      if (kc < 2) {
        va  = *(const uint4*)(LAz + (m0 + row) * 16 + kc * 8);
        vb_ = *(const uint4*)(LBz + (n0 + row) * 16 + kc * 8);
      } else {
        va.x = va.y = va.z = va.w = 0u; vb_ = va;
      }
      *(uint4*)(&As[0][h][ci * 8]) = va;
      *(uint4*)(&Bs[0][h][ci * 8]) = vb_;
    }
    __syncthreads();
    short8 a2[8], b2[4];
#pragma unroll
    for (int i = 0; i < 8; ++i)
      a2[i] = *(const short8*)(&As[0][wr][(i * 128 + lane) * 8]);
#pragma unroll
    for (int j = 0; j < 4; ++j)
      b2[j] = *(const short8*)(&Bs[0][wc >> 1][((bg + j) * 128 + lane) * 8]);
#pragma unroll
    for (int i = 0; i < 8; ++i)
#pragma unroll
      for (int j = 0; j < 4; ++j)
        acc[i][j] = __builtin_amdgcn_mfma_f32_16x16x32_bf16(a2[i], b2[j], acc[i][j], 0, 0, 0);
  } else {
    // drain in-flight LDS-DMA before the block can retire
    asm volatile("s_waitcnt vmcnt(0)" ::: "memory");
  }

#pragma unroll
  for (int i = 0; i < 8; ++i) {
    const long row = m0 + wr * 128 + i * 16 + quad * 4;
#pragma unroll
    for (int j = 0; j < 4; ++j) {
      const long col = n0 + wc * 64 + j * 16 + l16;
#pragma unroll
      for (int rr = 0; rr < 4; ++rr) {
        float val = acc[i][j][rr] * scale;
        if constexpr (OUTF32)
          ((float*)Cv)[(long)blockIdx.z * batC + (row + rr) * ldc + col] = val;
        else
          ((unsigned short*)Cv)[(long)blockIdx.z * batC + (row + rr) * ldc + col] = f2bf(val);
      }
    }
  }
#undef STG_A
#undef STG_B
}

__device__ __forceinline__ uint4 pack8(const float* x) {
  float4 a = *(const float4*)x;
  float4 b = *(const float4*)(x + 4);
  uint4 o;
  o.x = (unsigned int)f2bf(a.x) | ((unsigned int)f2bf(a.y) << 16);
  o.y = (unsigned int)f2bf(a.z) | ((unsigned int)f2bf(a.w) << 16);
  o.z = (unsigned int)f2bf(b.x) | ((unsigned int)f2bf(b.y) << 16);
  o.w = (unsigned int)f2bf(b.z) | ((unsigned int)f2bf(b.w) << 16);
  return o;
}

// pure fp32->bf16 convert of q/k/v. grid (512, 3), 16384 elems/block.
__global__ __launch_bounds__(256) void prep_qkv(
    const float* __restrict__ q, const float* __restrict__ k, const float* __restrict__ v,
    unsigned short* __restrict__ qb, unsigned short* __restrict__ kb,
    unsigned short* __restrict__ vb) {
  const float* X; unsigned short* Y;
  if (blockIdx.y == 0)      { X = q; Y = qb; }
  else if (blockIdx.y == 1) { X = k; Y = kb; }
  else                      { X = v; Y = vb; }
  const int tid = threadIdx.x;
  const long blk = (long)blockIdx.x * 16384;
#pragma unroll
  for (int it = 0; it < 8; ++it) {
    const long idx = blk + it * 2048 + tid * 8;
    *(uint4*)(Y + idx) = pack8(X + idx);
  }
}

// all weight converts in one dispatch. grid (512, 5):
//  y<4: big 1024x1024 matrices (Wq,Wk,Wv,Wo), x in [0,512)
//  y==4: six 16k matrices (QB,KB,VB,QA,KA,VA), x in [0,48): mat=x>>3, sub=x&7
__global__ __launch_bounds__(256) void cvt_all(
    const float* __restrict__ Wq, const float* __restrict__ Wk,
    const float* __restrict__ Wv, const float* __restrict__ Wo,
    const float* __restrict__ QB, const float* __restrict__ KB, const float* __restrict__ VB,
    const float* __restrict__ QA, const float* __restrict__ KA, const float* __restrict__ VA,
    unsigned short* __restrict__ wqb, unsigned short* __restrict__ wkb,
    unsigned short* __restrict__ wvb, unsigned short* __restrict__ wob,
    unsigned short* __restrict__ Bqb, unsigned short* __restrict__ Bkb, unsigned short* __restrict__ Bvb,
    unsigned short* __restrict__ Aqb, unsigned short* __restrict__ Akb, unsigned short* __restrict__ Avb) {
  if (blockIdx.y < 4) {
    const float* x; unsigned short* y;
    switch (blockIdx.y) {
      case 0: x = Wq; y = wqb; break;
      case 1: x = Wk; y = wkb; break;
      case 2: x = Wv; y = wvb; break;
      default: x = Wo; y = wob; break;
    }
    const long i = ((long)blockIdx.x * 256 + threadIdx.x) * 8;
    *(uint4*)(y + i) = pack8(x + i);
  } else {
    if (blockIdx.x >= 48) return;
    const int mat = blockIdx.x >> 3, sub = blockIdx.x & 7;
    const float* x; unsigned short* y;
    switch (mat) {
      case 0: x = QB; y = Bqb; break;
      case 1: x = KB; y = Bkb; break;
      case 2: x = VB; y = Bvb; break;
      case 3: x = QA; y = Aqb; break;
      case 4: x = KA; y = Akb; break;
      default: x = VA; y = Avb; break;
    }
    const long i = ((long)sub * 256 + threadIdx.x) * 8;
    *(uint4*)(y + i) = pack8(x + i);
  }
}

// T[8192][16] = Xb @ Am^T via MFMA. grid (128, 3): 64 rows/block, 16/wave.
__global__ __launch_bounds__(256) void lora_t_mfma(
    const unsigned short* __restrict__ qb, const unsigned short* __restrict__ kb,
    const unsigned short* __restrict__ vb,
    const unsigned short* __restrict__ Aq, const unsigned short* __restrict__ Ak,
    const unsigned short* __restrict__ Av,
    unsigned short* __restrict__ Tq, unsigned short* __restrict__ Tk,
    unsigned short* __restrict__ Tv) {
  const unsigned short* X; const unsigned short* Am; unsigned short* T;
  if (blockIdx.y == 0)      { X = qb; Am = Aq; T = Tq; }
  else if (blockIdx.y == 1) { X = kb; Am = Ak; T = Tk; }
  else                      { X = vb; Am = Av; T = Tv; }
  const int tid = threadIdx.x, wave = tid >> 6, lane = tid & 63;
  const int quad = lane >> 4, l16 = lane & 15;
  const long m0 = (long)blockIdx.x * 64 + wave * 16;
  floatx4 acc = (floatx4){0.f, 0.f, 0.f, 0.f};
  const unsigned short* xp = X + (m0 + l16) * 1024 + quad * 8;
  const unsigned short* ap = Am + (long)l16 * 1024 + quad * 8;
#pragma unroll 4
  for (int k0 = 0; k0 < 1024; k0 += 32) {
    short8 af = *(const short8*)(xp + k0);
    short8 bf = *(const short8*)(ap + k0);
    acc = __builtin_amdgcn_mfma_f32_16x16x32_bf16(af, bf, acc, 0, 0, 0);
  }
#pragma unroll
  for (int rr = 0; rr < 4; ++rr)
    T[(m0 + quad * 4 + rr) * 16 + l16] = f2bf(acc[rr]);
}

// in-place row softmax over 2048 bf16 scores; one block per row
__global__ __launch_bounds__(256) void softmax_kernel(unsigned short* __restrict__ S) {
  const long base = (long)blockIdx.x * 2048;
  const int tid = threadIdx.x;
  const int lane = tid & 63, wave = tid >> 6;
  __shared__ float redm[4], reds[4];
  uint4 raw = *(const uint4*)(S + base + tid * 8);
  unsigned int w[4] = {raw.x, raw.y, raw.z, raw.w};
  float v[8];
#pragma unroll
  for (int i = 0; i < 4; ++i) {
    v[2 * i]     = bf2f((unsigned short)(w[i] & 0xffffu));
    v[2 * i + 1] = bf2f((unsigned short)(w[i] >> 16));
  }
  float m = v[0];
#pragma unroll
  for (int i = 1; i < 8; ++i) m = fmaxf(m, v[i]);
  for (int off = 32; off >= 1; off >>= 1) m = fmaxf(m, __shfl_xor(m, off, 64));
  if (lane == 0) redm[wave] = m;
  __syncthreads();
  m = fmaxf(fmaxf(redm[0], redm[1]), fmaxf(redm[2], redm[3]));
  float e[8], s = 0.f;
#pragma unroll
  for (int i = 0; i < 8; ++i) { e[i] = __expf(v[i] - m); s += e[i]; }
  for (int off = 32; off >= 1; off >>= 1) s += __shfl_xor(s, off, 64);
  if (lane == 0) reds[wave] = s;
  __syncthreads();
  s = reds[0] + reds[1] + reds[2] + reds[3];
  const float inv = 1.0f / s;
  uint4 o;
  o.x = (unsigned int)f2bf(e[0] * inv) | ((unsigned int)f2bf(e[1] * inv) << 16);
  o.y = (unsigned int)f2bf(e[2] * inv) | ((unsigned int)f2bf(e[3] * inv) << 16);
  o.z = (unsigned int)f2bf(e[4] * inv) | ((unsigned int)f2bf(e[5] * inv) << 16);
  o.w = (unsigned int)f2bf(e[6] * inv) | ((unsigned int)f2bf(e[7] * inv) << 16);
  *(uint4*)(S + base + tid * 8) = o;
}

extern "C" void kernel_launch(void* const* d_in, const int* in_sizes, int n_in,
                              void* d_out, int out_size, void* d_ws, size_t ws_size,
                              hipStream_t stream) {
  const float* q  = (const float*)d_in[0];
  const float* k  = (const float*)d_in[1];
  const float* v  = (const float*)d_in[2];
  const float* Wq = (const float*)d_in[3];
  const float* Wk = (const float*)d_in[4];
  const float* Wv = (const float*)d_in[5];
  const float* QA = (const float*)d_in[6];
  const float* QB = (const float*)d_in[7];
  const float* KA = (const float*)d_in[8];
  const float* KB = (const float*)d_in[9];
  const float* VA = (const float*)d_in[10];
  const float* VB = (const float*)d_in[11];
  const float* Wo = (const float*)d_in[12];

  unsigned short* W = (unsigned short*)d_ws;
  const long SEe = (long)8192 * 1024;  // 8388608
  unsigned short* qb  = W;             // dead after Q-proj -> scores low half
  unsigned short* kb  = W + SEe;
  unsigned short* vb  = W + 2 * SEe;   // dead after V-proj -> attn buffer
  unsigned short* Qp  = W + 3 * SEe;
  unsigned short* Kp  = W + 4 * SEe;
  unsigned short* VT  = W + 5 * SEe;   // [1024][8192] = V^T
  unsigned short* wqb = W + 6 * SEe;
  unsigned short* wkb = wqb + 1048576;
  unsigned short* wvb = wkb + 1048576;
  unsigned short* wob = wvb + 1048576;
  unsigned short* Bqb = wob + 1048576;
  unsigned short* Bkb = Bqb + 16384;
  unsigned short* Bvb = Bkb + 16384;
  unsigned short* Aqb = Bvb + 16384;
  unsigned short* Akb = Aqb + 16384;
  unsigned short* Avb = Akb + 16384;
  unsigned short* Tq  = Avb + 16384;   // [8192][16]
  unsigned short* Tk  = Tq + 131072;
  unsigned short* Tv  = Tk + 131072;
  unsigned short* scores = W;          // [4][2048][2048] bf16, aliases qb+kb
  unsigned short* attn   = vb;         // [8192][1024] bf16, aliases vb

  dim3 blk(256, 1, 1), blk5(512, 1, 1);
  prep_qkv<<<dim3(512, 3, 1), blk, 0, stream>>>(q, k, v, qb, kb, vb);
  cvt_all<<<dim3(512, 5, 1), blk, 0, stream>>>(Wq, Wk, Wv, Wo, QB, KB, VB, QA, KA, VA,
                                               wqb, wkb, wvb, wob, Bqb, Bkb, Bvb, Aqb, Akb, Avb);
  lora_t_mfma<<<dim3(128, 3, 1), blk, 0, stream>>>(qb, kb, vb, Aqb, Akb, Avb, Tq, Tk, Tv);

  // Q = qb@Wq^T + Tq@Bq^T ; K likewise (z batches; M=8192,N=1024,K=1024)
  gemm256<true, false, true><<<dim3(4, 32, 2), blk5, 0, stream>>>(
      qb, wqb, Qp, Tq, Bqb, 1024, 1024, 1024, 1024, 1.0f,
      SEe, 1048576, SEe, 131072, 16384);
  // VT = Wv@vb^T + Bv@Tv^T  (M=1024,N=8192): OWNN (partition wide N)
  gemm256<true, false, false><<<dim3(32, 4, 1), blk5, 0, stream>>>(
      wvb, vb, VT, Bvb, Tv, 1024, 1024, 8192, 1024, 1.0f, 0, 0, 0, 0, 0);
  // scores = Qp@Kp^T / 32   (batched, M=N=2048,K=1024)
  gemm256<false, false, true><<<dim3(8, 8, 4), blk5, 0, stream>>>(
      Qp, Kp, scores, nullptr, nullptr, 1024, 1024, 2048, 1024, 0.03125f,
      (long)S_LEN * E_DIM, (long)S_LEN * E_DIM, (long)S_LEN * S_LEN, 0, 0);
  softmax_kernel<<<8192, blk, 0, stream>>>(scores);
  // attn_out = P@V = P@(VT)^T  (batched, M=2048,N=1024,K=2048)
  gemm256<false, false, true><<<dim3(4, 8, 4), blk5, 0, stream>>>(
      scores, VT, attn, nullptr, nullptr, 2048, 8192, 1024, 2048, 1.0f,
      (long)S_LEN * S_LEN, (long)S_LEN, (long)S_LEN * E_DIM, 0, 0);
  // final = attn@Wo^T -> fp32 d_out  (M=8192,N=1024,K=1024)
  gemm256<false, true, true><<<dim3(4, 32, 1), blk5, 0, stream>>>(
      attn, wob, d_out, nullptr, nullptr, 1024, 1024, 1024, 1024, 1.0f, 0, 0, 0, 0, 0);
}